// Round 9
// baseline (361.009 us; speedup 1.0000x reference)
//
#include <hip/hip_runtime.h>
#include <cstdint>
#include <cstddef>

// Problem constants
#define NN    50000
#define EE    800000   /* graph edges; self-loops handled analytically in agg */
#define SLOPE 0.2f
#define MT64  782      /* (NN+63)/64 row-blocks */
#define CAP   64       /* per-node bucket capacity (in-deg Poisson(16), P(>=64)~1e-20) */

// Two-level binning scatter. Round-7 lesson: oversubscribed fused grids run
// blocks in ID order -> put the small phase FIRST so it hides under the bulk.
#define NBIN  196
#define DSH   8        /* dst>>DSH = bin; 256 nodes per bin */
#define PBLK  1024     /* phase-1 scatter blocks */
#define EPB   782      /* ceil(EE/PBLK) */
#define BCAP  14       /* per-(block,bin) cap; lambda~4.0, P(Pois(4)>14)~2e-5 */
#define OCAP  8192     /* global overflow list capacity */
#define CASTB 20       /* 16 W1 64x64 tiles + 4 W2 tiles */
#define BUCKB NBIN     /* bucket blocks, first in d2 */

// Round-9: XCD-sliced agg1. h1b stored slice-major (slice=col/32, 8 slices of
// 3.2MB). agg1 task=(node,slice), slice=blockIdx&7 -> round-robin XCD mapping
// pins each slice to one XCD whose 3.2MB slice is L2-RESIDENT. Old layout:
// every XCD streamed all 25.6MB (FETCH=209MB=8x25.6, r8 counters).
#define SLW   32       /* cols per slice */

typedef unsigned short ushortT;
typedef __attribute__((ext_vector_type(8))) short short8;
typedef __attribute__((ext_vector_type(4))) float floatx4;

__device__ __forceinline__ float lrelu(float x){ return x > 0.f ? x : SLOPE * x; }
__device__ __forceinline__ float eluf(float x){ return x > 0.f ? x : __expf(x) - 1.f; }
__device__ __forceinline__ ushortT f2b(float f){ unsigned u = __float_as_uint(f); u += 0x7fff + ((u >> 16) & 1); return (ushortT)(u >> 16); }
__device__ __forceinline__ float   b2f(ushortT b){ return __uint_as_float(((unsigned)b) << 16); }

// ---------------------------------------------------------------------------
// d1: blocks [0,CASTB) = LDS-tiled weight transpose-cast (coalesced writes);
// blocks [CASTB,..) = phase-1 edge binning. castW first, hides under binning.
// ---------------------------------------------------------------------------
__global__ __launch_bounds__(256, 3) void binCast_k(const int* __restrict__ srcA,
                                                    const int* __restrict__ dstA,
                                                    unsigned* __restrict__ binned,
                                                    ushortT* __restrict__ cnt2,
                                                    unsigned* __restrict__ ovf,
                                                    int* __restrict__ ovfcnt,
                                                    const float* __restrict__ W1,
                                                    const float* __restrict__ W2,
                                                    ushortT* __restrict__ W1T,
                                                    ushortT* __restrict__ W2T)
{
    __shared__ float    tile[64][65];        // 16.6 KB (transpose staging)
    __shared__ int      hist[NBIN];          // 784 B
    __shared__ unsigned lrec[NBIN][BCAP];    // 11 KB

    const int tid = threadIdx.x;
    if (blockIdx.x < CASTB) {
        const int lr = tid >> 6;       // 0..3
        const int lc = tid & 63;       // 0..63
        if (blockIdx.x < 16) {
            const int tr = blockIdx.x >> 2, tc = blockIdx.x & 3;
            #pragma unroll
            for (int i = 0; i < 16; ++i) {
                int r = lr + i * 4;
                tile[r][lc] = W1[(size_t)(tr * 64 + r) * 256 + tc * 64 + lc];
            }
            __syncthreads();
            #pragma unroll
            for (int i = 0; i < 16; ++i) {
                int r = lr + i * 4;
                W1T[(size_t)(tc * 64 + r) * 256 + tr * 64 + lc] = f2b(tile[lc][r]);
            }
        } else {
            const int tk = blockIdx.x - 16;   // 0..3 over k
            #pragma unroll
            for (int i = 0; i < 16; ++i) {
                int r = lr + i * 4;
                tile[r][lc] = W2[(size_t)(tk * 64 + r) * 64 + lc];
            }
            __syncthreads();
            #pragma unroll
            for (int i = 0; i < 16; ++i) {
                int r = lr + i * 4;
                W2T[(size_t)r * 256 + tk * 64 + lc] = f2b(tile[lc][r]);
            }
        }
        return;
    }

    // ---- phase-1 binning ----
    const int blk = blockIdx.x - CASTB;
    for (int i = tid; i < NBIN; i += 256) hist[i] = 0;
    __syncthreads();

    const int e0 = blk * EPB;
    const int e1 = min(e0 + EPB, EE);
    for (int e = e0 + tid; e < e1; e += 256) {
        int s = srcA[e], d = dstA[e];
        int bin = d >> DSH;
        unsigned rec = ((unsigned)s << DSH) | (unsigned)(d & 255);
        int r = atomicAdd(&hist[bin], 1);
        if (r < BCAP) lrec[bin][r] = rec;
        else {
            int o = atomicAdd(ovfcnt, 1);
            if (o < OCAP) ovf[o] = ((unsigned)s << 16) | (unsigned)d;
        }
    }
    __syncthreads();

    for (int b = tid; b < NBIN; b += 256)
        cnt2[(size_t)blk * NBIN + b] = (ushortT)min(hist[b], BCAP);
    for (int sIdx = tid; sIdx < NBIN * BCAP; sIdx += 256) {
        int b = sIdx / BCAP;
        int i = sIdx - b * BCAP;
        if (i < min(hist[b], BCAP))
            binned[((size_t)blk * NBIN + b) * BCAP + i] = lrec[b][i];
    }
}

// ---------------------------------------------------------------------------
// d2: blocks [0,BUCKB) = phase-2 bucket assembly (first, hides under GEMM);
// blocks [BUCKB,..) = layer-1 GEMM writing h1b in SLICE-MAJOR layout:
// h1b[slice*NN*32 + row*32 + (col&31)], slice = col>>5.
// ---------------------------------------------------------------------------
__global__ __launch_bounds__(256, 3) void gembucket_k(const float* __restrict__ x,
                                                      const ushortT* __restrict__ W1T,
                                                      const float* __restrict__ attS,
                                                      const float* __restrict__ attD,
                                                      ushortT* __restrict__ h1b,
                                                      float* __restrict__ asrc,
                                                      float* __restrict__ adst,
                                                      const unsigned* __restrict__ binned,
                                                      const ushortT* __restrict__ cnt2,
                                                      const unsigned* __restrict__ ovf,
                                                      const int* __restrict__ ovfcnt,
                                                      ushortT* __restrict__ esorted,
                                                      int* __restrict__ cnt)
{
    __shared__ ushortT c2[PBLK];          // 2 KB
    __shared__ int     lcnt[256];         // 1 KB
    __shared__ ushortT lbuck[256][CAP];   // 32 KB

    const int tid = threadIdx.x;
    if (blockIdx.x < BUCKB) {
        const int b = blockIdx.x;
        lcnt[tid] = 0;
        for (int i = tid; i < PBLK; i += 256) c2[i] = cnt2[(size_t)i * NBIN + b];
        __syncthreads();

        for (int s0 = tid; s0 < PBLK * BCAP; s0 += 2048) {
            unsigned recs[8]; int ok[8];
            #pragma unroll
            for (int q = 0; q < 8; ++q) {
                int s = s0 + q * 256;
                int blk = s / BCAP;
                int i = s - blk * BCAP;
                ok[q] = (i < (int)c2[blk]);
                recs[q] = ok[q] ? binned[((size_t)blk * NBIN + b) * BCAP + i] : 0u;
            }
            #pragma unroll
            for (int q = 0; q < 8; ++q) {
                if (ok[q]) {
                    int dl = recs[q] & 255;
                    int r = atomicAdd(&lcnt[dl], 1);
                    if (r < CAP) lbuck[dl][r] = (ushortT)(recs[q] >> DSH);
                }
            }
        }

        int nov = *ovfcnt;
        nov = nov > OCAP ? OCAP : nov;
        for (int i = tid; i < nov; i += 256) {
            unsigned rec = ovf[i];
            int d = rec & 0xFFFF;
            if ((d >> DSH) == b) {
                int r = atomicAdd(&lcnt[d & 255], 1);
                if (r < CAP) lbuck[d & 255][r] = (ushortT)(rec >> 16);
            }
        }
        __syncthreads();

        const int nbase = b << DSH;
        {
            int n = nbase + tid;
            if (n < NN) cnt[n] = lcnt[tid];
        }
        unsigned* ed = (unsigned*)(esorted + (size_t)nbase * CAP);
        const unsigned* ls = (const unsigned*)(&lbuck[0][0]);
        for (int i = tid; i < 256 * (CAP / 2); i += 256) {
            if (nbase + (i >> 5) < NN) ed[i] = ls[i];
        }
        return;
    }

    // ---- LDS-free GEMM1: 64x256 block, 2x2 waves, wave tile 32x128 ----
    const int w    = tid >> 6;
    const int lane = tid & 63;
    const int m16  = lane & 15;
    const int quad = lane >> 4;
    const int wr   = w >> 1;
    const int wc   = w & 1;
    const int gb   = blockIdx.x - BUCKB;
    const int rowbase = gb * 64 + wr * 32;
    const int colbase = wc * 128;

    const long r0 = min(rowbase + m16,      NN - 1);
    const long r1 = min(rowbase + 16 + m16, NN - 1);
    const float* a0p = x + r0 * 256 + quad * 8;
    const float* a1p = x + r1 * 256 + quad * 8;
    const ushortT* bp0 = W1T + (size_t)(colbase + m16) * 256 + quad * 8;

    floatx4 acc[2][8];
    #pragma unroll
    for (int i = 0; i < 2; ++i)
        #pragma unroll
        for (int j = 0; j < 8; ++j) acc[i][j] = (floatx4){0.f, 0.f, 0.f, 0.f};

    #pragma unroll
    for (int it = 0; it < 8; ++it) {
        const int k0 = it * 32;
        float4 fa00 = *(const float4*)(a0p + k0);
        float4 fa01 = *(const float4*)(a0p + k0 + 4);
        float4 fa10 = *(const float4*)(a1p + k0);
        float4 fa11 = *(const float4*)(a1p + k0 + 4);
        uint4 fb[8];
        #pragma unroll
        for (int j = 0; j < 8; ++j)
            fb[j] = *(const uint4*)(bp0 + (size_t)j * 16 * 256 + k0);

        ushortT a16[16];
        a16[0]=f2b(fa00.x); a16[1]=f2b(fa00.y); a16[2]=f2b(fa00.z); a16[3]=f2b(fa00.w);
        a16[4]=f2b(fa01.x); a16[5]=f2b(fa01.y); a16[6]=f2b(fa01.z); a16[7]=f2b(fa01.w);
        a16[8]=f2b(fa10.x); a16[9]=f2b(fa10.y); a16[10]=f2b(fa10.z); a16[11]=f2b(fa10.w);
        a16[12]=f2b(fa11.x); a16[13]=f2b(fa11.y); a16[14]=f2b(fa11.z); a16[15]=f2b(fa11.w);
        short8 af0 = *(short8*)(a16);
        short8 af1 = *(short8*)(a16 + 8);

        #pragma unroll
        for (int j = 0; j < 8; ++j) {
            short8 bf = *(short8*)(&fb[j]);
            acc[0][j] = __builtin_amdgcn_mfma_f32_16x16x32_bf16(af0, bf, acc[0][j], 0, 0, 0);
            acc[1][j] = __builtin_amdgcn_mfma_f32_16x16x32_bf16(af1, bf, acc[1][j], 0, 0, 0);
        }
    }

    float attSv[8], attDv[8];
    #pragma unroll
    for (int j = 0; j < 8; ++j) {
        attSv[j] = attS[colbase + j * 16 + m16];
        attDv[j] = attD[colbase + j * 16 + m16];
    }

    #pragma unroll
    for (int i = 0; i < 2; ++i) {
        #pragma unroll
        for (int r = 0; r < 4; ++r) {
            int row = rowbase + i * 16 + quad * 4 + r;
            bool ok = row < NN;
            if (ok) {
                #pragma unroll
                for (int j = 0; j < 8; ++j) {
                    int sl = (colbase >> 5) + (j >> 1);         // slice = col>>5
                    int cc = ((j & 1) << 4) + m16;              // col within slice
                    h1b[(size_t)sl * NN * SLW + (size_t)row * SLW + cc] = f2b(acc[i][j][r]);
                }
            }
            float d0 = 0.f, d1 = 0.f, e0 = 0.f, e1 = 0.f;
            #pragma unroll
            for (int jj = 0; jj < 4; ++jj) {
                d0 += acc[i][jj][r]     * attSv[jj];
                e0 += acc[i][jj][r]     * attDv[jj];
                d1 += acc[i][jj + 4][r] * attSv[jj + 4];
                e1 += acc[i][jj + 4][r] * attDv[jj + 4];
            }
            #pragma unroll
            for (int off = 1; off < 16; off <<= 1) {
                d0 += __shfl_xor(d0, off); e0 += __shfl_xor(e0, off);
                d1 += __shfl_xor(d1, off); e1 += __shfl_xor(e1, off);
            }
            if (ok && m16 == 0) {
                int hb = row * 4 + wc * 2;
                asrc[hb] = d0; asrc[hb + 1] = d1;
                adst[hb] = e0; adst[hb + 1] = e1;
            }
        }
    }
}

// ---------------------------------------------------------------------------
// agg1, XCD-sliced: task = (node, slice). slice = blockIdx&7 -> round-robin
// XCD mapping keeps each 3.2MB h1b slice L2-resident on one XCD. One wave
// per node: p computed by lane=edge, broadcast via shfl; gather loop does
// 8 edges x 8 col-chunks (ushort4/lane); strided shfl_xor reduce; lanes 0..7
// add self-loop, apply softmax-normalize + bias + elu, write 64B a2b slice.
// ---------------------------------------------------------------------------
__global__ __launch_bounds__(256) void agg1_k(const ushortT* __restrict__ esorted,
                                              const int* __restrict__ cnt,
                                              const ushortT* __restrict__ h1b,
                                              const float* __restrict__ asrc,
                                              const float* __restrict__ adst,
                                              const float* __restrict__ b1,
                                              ushortT* __restrict__ a2b)
{
    const int slice = blockIdx.x & 7;
    const int grp   = blockIdx.x >> 3;
    const int wv    = threadIdx.x >> 6;
    const int lane  = threadIdx.x & 63;
    const int n     = grp * 4 + wv;
    if (n >= NN) return;
    const int h = slice >> 1;
    const ushortT* hs = h1b + (size_t)slice * NN * SLW;

    int deg = min(max(cnt[n], 0), CAP);
    float adv = adst[(size_t)n * 4 + h];
    float pself = __expf(lrelu(asrc[(size_t)n * 4 + h] + adv));

    int   s_reg = 0;
    float p_reg = 0.f;
    if (lane < deg) {
        s_reg = esorted[(size_t)n * CAP + lane];
        p_reg = __expf(lrelu(asrc[(size_t)s_reg * 4 + h] + adv));
    }
    float ss = p_reg;
    #pragma unroll
    for (int off = 1; off < 64; off <<= 1) ss += __shfl_xor(ss, off);
    float rdh = 1.f / (ss + pself);

    float4 acc = make_float4(0.f, 0.f, 0.f, 0.f);
    const int nb = (deg + 7) >> 3;     // wave-uniform
    const int eg = lane >> 3;          // edge subgroup 0..7
    const int cw = lane & 7;           // col chunk 0..7
    for (int b = 0; b < nb; ++b) {
        int e = b * 8 + eg;            // < 64 always
        int s = __shfl(s_reg, e);
        float p = __shfl(p_reg, e);    // 0 for padded edges (s=0 harmless)
        ushort4 hv = *(const ushort4*)(hs + (size_t)s * SLW + cw * 4);
        acc.x += b2f(hv.x) * p; acc.y += b2f(hv.y) * p;
        acc.z += b2f(hv.z) * p; acc.w += b2f(hv.w) * p;
    }
    #pragma unroll
    for (int off = 8; off < 64; off <<= 1) {
        acc.x += __shfl_xor(acc.x, off); acc.y += __shfl_xor(acc.y, off);
        acc.z += __shfl_xor(acc.z, off); acc.w += __shfl_xor(acc.w, off);
    }

    if (lane < 8) {
        ushort4 hv = *(const ushort4*)(hs + (size_t)n * SLW + lane * 4);
        acc.x += b2f(hv.x) * pself; acc.y += b2f(hv.y) * pself;
        acc.z += b2f(hv.z) * pself; acc.w += b2f(hv.w) * pself;
        float4 bv = *(const float4*)(b1 + slice * SLW + lane * 4);
        ushort4 o;
        o.x = f2b(eluf(acc.x * rdh + bv.x));
        o.y = f2b(eluf(acc.y * rdh + bv.y));
        o.z = f2b(eluf(acc.z * rdh + bv.z));
        o.w = f2b(eluf(acc.w * rdh + bv.w));
        *(ushort4*)(a2b + (size_t)n * 256 + slice * SLW + lane * 4) = o;
    }
}

// ---------------------------------------------------------------------------
// Layer-2 GEMM, LDS-free. Wave tile 16x64; 4 waves stacked = 64 rows.
// ---------------------------------------------------------------------------
__global__ __launch_bounds__(256) void gemm2_k(const ushortT* __restrict__ a2b,
                                               const ushortT* __restrict__ W2T,
                                               const float* __restrict__ attS,
                                               const float* __restrict__ attD,
                                               ushortT* __restrict__ t2b,
                                               float* __restrict__ asrc,
                                               float* __restrict__ adst)
{
    const int tid  = threadIdx.x;
    const int w    = tid >> 6;
    const int lane = tid & 63;
    const int m16  = lane & 15;
    const int quad = lane >> 4;
    const int rowbase = blockIdx.x * 64 + w * 16;

    const long r0 = min(rowbase + m16, NN - 1);
    const ushortT* ap  = a2b + r0 * 256 + quad * 8;
    const ushortT* bp0 = W2T + (size_t)m16 * 256 + quad * 8;

    floatx4 acc[4];
    #pragma unroll
    for (int j = 0; j < 4; ++j) acc[j] = (floatx4){0.f, 0.f, 0.f, 0.f};

    #pragma unroll
    for (int it = 0; it < 8; ++it) {
        const int k0 = it * 32;
        uint4 fa = *(const uint4*)(ap + k0);
        uint4 fb[4];
        #pragma unroll
        for (int j = 0; j < 4; ++j)
            fb[j] = *(const uint4*)(bp0 + (size_t)j * 16 * 256 + k0);
        short8 af = *(short8*)(&fa);
        #pragma unroll
        for (int j = 0; j < 4; ++j) {
            short8 bf = *(short8*)(&fb[j]);
            acc[j] = __builtin_amdgcn_mfma_f32_16x16x32_bf16(af, bf, acc[j], 0, 0, 0);
        }
    }

    float attSv[4], attDv[4];
    #pragma unroll
    for (int j = 0; j < 4; ++j) {
        attSv[j] = attS[j * 16 + m16];
        attDv[j] = attD[j * 16 + m16];
    }

    #pragma unroll
    for (int r = 0; r < 4; ++r) {
        int row = rowbase + quad * 4 + r;
        bool ok = row < NN;
        if (ok) {
            #pragma unroll
            for (int j = 0; j < 4; ++j)
                t2b[(size_t)row * 64 + j * 16 + m16] = f2b(acc[j][r]);
        }
        float ds = 0.f, dd = 0.f;
        #pragma unroll
        for (int j = 0; j < 4; ++j) {
            ds += acc[j][r] * attSv[j];
            dd += acc[j][r] * attDv[j];
        }
        #pragma unroll
        for (int off = 1; off < 16; off <<= 1) {
            ds += __shfl_xor(ds, off);
            dd += __shfl_xor(dd, off);
        }
        if (ok && m16 == 0) {
            asrc[row] = ds;
            adst[row] = dd;
        }
    }
}

// ---------------------------------------------------------------------------
// agg2 (passing version, unchanged).
// ---------------------------------------------------------------------------
__global__ __launch_bounds__(256) void agg2_k(const ushortT* __restrict__ esorted,
                                              const int* __restrict__ cnt,
                                              const ushortT* __restrict__ t2b,
                                              const float* __restrict__ asrc,
                                              const float* __restrict__ adst,
                                              const float* __restrict__ b2,
                                              float* __restrict__ out)
{
    __shared__ float pbuf[4][64];
    __shared__ int   sbuf[4][64];
    int w = threadIdx.x >> 6;
    int lane = threadIdx.x & 63;
    int n = blockIdx.x * 4 + w;
    if (n >= NN) return;
    int start = n * CAP;
    int deg = min(max(cnt[n], 0), CAP);
    float adv = adst[n];

    float pself = __expf(lrelu(asrc[n] + adv));
    float a0 = b2f(t2b[(size_t)n * 64 + lane]) * pself;
    float a1 = 0.f, a2 = 0.f, a3 = 0.f;
    float ss = 0.f;

    if (lane < deg) {
        int s = esorted[start + lane];
        float p = __expf(lrelu(asrc[s] + adv));
        ss = p;
        pbuf[w][lane] = p;
        sbuf[w][lane] = s;
    } else {
        pbuf[w][lane] = 0.f;
        sbuf[w][lane] = 0;
    }
    __builtin_amdgcn_wave_barrier();

    int nb = (deg + 7) >> 3;           // 0..8
    ushortT bufA[8], bufB[8];

#define LOADR2(BUF, J0) { _Pragma("unroll") for (int q = 0; q < 8; ++q) { \
        int sq = sbuf[w][(J0) + q]; \
        BUF[q] = t2b[(size_t)sq * 64 + lane]; } }
#define CONSR2(BUF, J0) { _Pragma("unroll") for (int q = 0; q < 8; ++q) { \
        float p = pbuf[w][(J0) + q]; \
        float* ac = (q & 3) == 0 ? &a0 : (q & 3) == 1 ? &a1 : (q & 3) == 2 ? &a2 : &a3; \
        *ac += b2f(BUF[q]) * p; } }

    if (nb > 0) {
        LOADR2(bufA, 0)
        #pragma unroll
        for (int b = 0; b < 8; ++b) {
            const int j0 = b << 3;
            if (b & 1) {
                if (b + 1 < nb) LOADR2(bufA, j0 + 8)
                CONSR2(bufB, j0)
            } else {
                if (b + 1 < nb) LOADR2(bufB, j0 + 8)
                CONSR2(bufA, j0)
            }
            if (b + 1 >= nb) break;
        }
    }
#undef LOADR2
#undef CONSR2

    #pragma unroll
    for (int off = 1; off < 64; off <<= 1) ss += __shfl_xor(ss, off);
    float v = (a0 + a1 + a2 + a3) / (ss + pself) + b2[lane];

    float m2 = v;
    #pragma unroll
    for (int off = 32; off; off >>= 1) m2 = fmaxf(m2, __shfl_xor(m2, off));
    float ex = __expf(v - m2);
    float sm = ex;
    #pragma unroll
    for (int off = 32; off; off >>= 1) sm += __shfl_xor(sm, off);
    out[(size_t)n * 64 + lane] = v - m2 - __logf(sm);
}

// ---------------------------------------------------------------------------
extern "C" void kernel_launch(void* const* d_in, const int* in_sizes, int n_in,
                              void* d_out, int out_size, void* d_ws, size_t ws_size,
                              hipStream_t stream)
{
    const float* x   = (const float*)d_in[0];
    const int*   adj = (const int*)  d_in[1];
    const float* W1  = (const float*)d_in[2];
    const float* as1 = (const float*)d_in[3];
    const float* ad1 = (const float*)d_in[4];
    const float* b1  = (const float*)d_in[5];
    const float* W2  = (const float*)d_in[6];
    const float* as2 = (const float*)d_in[7];
    const float* ad2 = (const float*)d_in[8];
    const float* b2  = (const float*)d_in[9];
    float* out = (float*)d_out;

    const size_t szH1b = (size_t)NN * 256 * 2;           // 25.6 MB (8 slices x 3.2MB)
    const size_t szT2b = (size_t)NN * 64 * 2;            // 6.4 MB
    const size_t szA4  = (size_t)NN * 4 * 4;             // 0.8 MB
    const size_t szA1  = (size_t)NN * 4;                 // 0.2 MB
    const size_t szE   = (size_t)NN * CAP * 2;           // 6.4 MB (ushort buckets)
    const size_t szBin = (size_t)NBIN * PBLK * BCAP * 4; // 11.2 MB (phase-1 records)
    const size_t szC2  = (size_t)PBLK * NBIN * 2;        // 0.4 MB (per-(block,bin) counts)

    char* p = (char*)d_ws;
    ushortT* h1b  = (ushortT*)p; p += szH1b;
    ushortT* a2b  = (ushortT*)p; p += szH1b;
    ushortT* t2b  = (ushortT*)p; p += szT2b;
    ushortT* W1T  = (ushortT*)p; p += 256 * 256 * 2;
    ushortT* W2T  = (ushortT*)p; p += 64 * 256 * 2;
    float* asrc1  = (float*)p; p += szA4;
    float* adst1  = (float*)p; p += szA4;
    float* asrc2  = (float*)p; p += szA1;
    float* adst2  = (float*)p; p += szA1;
    ushortT* esorted = (ushortT*)p; p += szE;
    int* cnt      = (int*)p; p += szA1;
    unsigned* binned = (unsigned*)p; p += szBin;
    ushortT* cnt2 = (ushortT*)p; p += szC2;
    unsigned* ovf = (unsigned*)p; p += (size_t)OCAP * 4;
    int* ovfcnt   = (int*)p; p += 64;

    const int nwb = (NN + 3) / 4;       // 12500

    // overflow-counter zero (graph-capture-legal async memset)
    hipMemsetAsync(ovfcnt, 0, sizeof(int), stream);

    // d1: LDS-tiled castW (blocks 0..19, hides under bin) + phase-1 binning
    binCast_k<<<CASTB + PBLK, 256, 0, stream>>>(adj, adj + EE, binned, cnt2, ovf, ovfcnt,
                                                W1, W2, W1T, W2T);

    // d2: bucket assembly (blocks 0..195, hides under gemm) + layer-1 GEMM
    gembucket_k<<<BUCKB + MT64, 256, 0, stream>>>(x, W1T, as1, ad1, h1b, asrc1, adst1,
                                                  binned, cnt2, ovf, ovfcnt, esorted, cnt);

    // XCD-sliced agg1: (node, slice) tasks; slice = blockIdx & 7
    agg1_k<<<nwb * 8, 256, 0, stream>>>(esorted, cnt, h1b, asrc1, adst1, b1, a2b);

    gemm2_k<<<MT64, 256, 0, stream>>>(a2b, W2T, as2, ad2, t2b, asrc2, adst2);
    agg2_k<<<nwb, 256, 0, stream>>>(esorted, cnt, t2b, asrc2, adst2, b2, out);
}

// Round 10
// 344.828 us; speedup vs baseline: 1.0469x; 1.0469x over previous
//
#include <hip/hip_runtime.h>
#include <cstdint>
#include <cstddef>

// Problem constants
#define NN    50000
#define EE    800000   /* graph edges; self-loops handled analytically in agg */
#define SLOPE 0.2f
#define MT64  782      /* (NN+63)/64 row-blocks */
#define CAP   64       /* per-node bucket capacity (in-deg Poisson(16), P(>=64)~1e-20) */

// Two-level binning scatter. Round-7 lesson: oversubscribed fused grids run
// blocks in ID order -> put the small phase FIRST so it hides under the bulk.
// Round-9 lesson: XCD-sliced agg1 halved fabric FETCH (209->111MB) but 2.5x'd
// time (instruction-bound: per-(node,slice) fixed overhead x8). Reverted;
// agg1's 66us = fabric floor for the row-gather structure.
#define NBIN  196
#define DSH   8        /* dst>>DSH = bin; 256 nodes per bin */
#define PBLK  1024     /* phase-1 scatter blocks */
#define EPB   782      /* ceil(EE/PBLK) */
#define BCAP  14       /* per-(block,bin) cap; lambda~4.0, P(Pois(4)>14)~2e-5 */
#define OCAP  8192     /* global overflow list capacity */
#define CASTB 20       /* 16 W1 64x64 tiles + 4 W2 pack blocks */
#define BUCKB NBIN     /* bucket blocks, first in d2 */

typedef unsigned short ushortT;
typedef __attribute__((ext_vector_type(8))) short short8;
typedef __attribute__((ext_vector_type(4))) float floatx4;

__device__ __forceinline__ float lrelu(float x){ return x > 0.f ? x : SLOPE * x; }
__device__ __forceinline__ float eluf(float x){ return x > 0.f ? x : __expf(x) - 1.f; }
__device__ __forceinline__ ushortT f2b(float f){ unsigned u = __float_as_uint(f); u += 0x7fff + ((u >> 16) & 1); return (ushortT)(u >> 16); }
__device__ __forceinline__ float   b2f(ushortT b){ return __uint_as_float(((unsigned)b) << 16); }

// ---------------------------------------------------------------------------
// d1: blocks [0,CASTB) = weight prep; blocks [CASTB,..) = phase-1 binning.
// Blocks 0..15: LDS-tiled W1 transpose-cast (coalesced writes).
// Blocks 16..19: W2 packed k-major cast W2P[q][j][r] = W2[4q+r][j] — lets the
// agg1-fused layer-2 epilogue load 512B contiguous per k-group (round-10).
// ---------------------------------------------------------------------------
__global__ __launch_bounds__(256, 3) void binCast_k(const int* __restrict__ srcA,
                                                    const int* __restrict__ dstA,
                                                    unsigned* __restrict__ binned,
                                                    ushortT* __restrict__ cnt2,
                                                    unsigned* __restrict__ ovf,
                                                    int* __restrict__ ovfcnt,
                                                    const float* __restrict__ W1,
                                                    const float* __restrict__ W2,
                                                    ushortT* __restrict__ W1T,
                                                    ushortT* __restrict__ W2P)
{
    __shared__ float    tile[64][65];        // 16.6 KB (transpose staging)
    __shared__ int      hist[NBIN];          // 784 B
    __shared__ unsigned lrec[NBIN][BCAP];    // 11 KB

    const int tid = threadIdx.x;
    if (blockIdx.x < CASTB) {
        if (blockIdx.x < 16) {
            const int lr = tid >> 6;       // 0..3
            const int lc = tid & 63;       // 0..63
            const int tr = blockIdx.x >> 2, tc = blockIdx.x & 3;
            #pragma unroll
            for (int i = 0; i < 16; ++i) {
                int r = lr + i * 4;
                tile[r][lc] = W1[(size_t)(tr * 64 + r) * 256 + tc * 64 + lc];
            }
            __syncthreads();
            #pragma unroll
            for (int i = 0; i < 16; ++i) {
                int r = lr + i * 4;
                W1T[(size_t)(tc * 64 + r) * 256 + tr * 64 + lc] = f2b(tile[lc][r]);
            }
        } else {
            // W2 (256x64 f32, [k][j]) -> W2P packed: [q][j][r], q=k>>2, r=k&3
            const int tk = blockIdx.x - 16;   // 0..3 -> q range 16tk..16tk+15
            for (int p4 = tid; p4 < 1024; p4 += 256) {
                int q = tk * 16 + (p4 >> 6);
                int j = p4 & 63;
                ushort4 o4;
                o4.x = f2b(W2[(size_t)(4 * q + 0) * 64 + j]);
                o4.y = f2b(W2[(size_t)(4 * q + 1) * 64 + j]);
                o4.z = f2b(W2[(size_t)(4 * q + 2) * 64 + j]);
                o4.w = f2b(W2[(size_t)(4 * q + 3) * 64 + j]);
                *(ushort4*)(W2P + ((size_t)q * 64 + j) * 4) = o4;
            }
        }
        return;
    }

    // ---- phase-1 binning ----
    const int blk = blockIdx.x - CASTB;
    for (int i = tid; i < NBIN; i += 256) hist[i] = 0;
    __syncthreads();

    const int e0 = blk * EPB;
    const int e1 = min(e0 + EPB, EE);
    for (int e = e0 + tid; e < e1; e += 256) {
        int s = srcA[e], d = dstA[e];
        int bin = d >> DSH;
        unsigned rec = ((unsigned)s << DSH) | (unsigned)(d & 255);
        int r = atomicAdd(&hist[bin], 1);
        if (r < BCAP) lrec[bin][r] = rec;
        else {
            int o = atomicAdd(ovfcnt, 1);
            if (o < OCAP) ovf[o] = ((unsigned)s << 16) | (unsigned)d;
        }
    }
    __syncthreads();

    for (int b = tid; b < NBIN; b += 256)
        cnt2[(size_t)blk * NBIN + b] = (ushortT)min(hist[b], BCAP);
    for (int sIdx = tid; sIdx < NBIN * BCAP; sIdx += 256) {
        int b = sIdx / BCAP;
        int i = sIdx - b * BCAP;
        if (i < min(hist[b], BCAP))
            binned[((size_t)blk * NBIN + b) * BCAP + i] = lrec[b][i];
    }
}

// ---------------------------------------------------------------------------
// d2: blocks [0,BUCKB) = phase-2 bucket assembly (first, hides under GEMM);
// blocks [BUCKB,..) = layer-1 GEMM (row-major h1b store, round-8 verbatim).
// ---------------------------------------------------------------------------
__global__ __launch_bounds__(256, 3) void gembucket_k(const float* __restrict__ x,
                                                      const ushortT* __restrict__ W1T,
                                                      const float* __restrict__ attS,
                                                      const float* __restrict__ attD,
                                                      ushortT* __restrict__ h1b,
                                                      float* __restrict__ asrc,
                                                      float* __restrict__ adst,
                                                      const unsigned* __restrict__ binned,
                                                      const ushortT* __restrict__ cnt2,
                                                      const unsigned* __restrict__ ovf,
                                                      const int* __restrict__ ovfcnt,
                                                      ushortT* __restrict__ esorted,
                                                      int* __restrict__ cnt)
{
    __shared__ ushortT c2[PBLK];          // 2 KB
    __shared__ int     lcnt[256];         // 1 KB
    __shared__ ushortT lbuck[256][CAP];   // 32 KB

    const int tid = threadIdx.x;
    if (blockIdx.x < BUCKB) {
        const int b = blockIdx.x;
        lcnt[tid] = 0;
        for (int i = tid; i < PBLK; i += 256) c2[i] = cnt2[(size_t)i * NBIN + b];
        __syncthreads();

        for (int s0 = tid; s0 < PBLK * BCAP; s0 += 2048) {
            unsigned recs[8]; int ok[8];
            #pragma unroll
            for (int q = 0; q < 8; ++q) {
                int s = s0 + q * 256;
                int blk = s / BCAP;
                int i = s - blk * BCAP;
                ok[q] = (i < (int)c2[blk]);
                recs[q] = ok[q] ? binned[((size_t)blk * NBIN + b) * BCAP + i] : 0u;
            }
            #pragma unroll
            for (int q = 0; q < 8; ++q) {
                if (ok[q]) {
                    int dl = recs[q] & 255;
                    int r = atomicAdd(&lcnt[dl], 1);
                    if (r < CAP) lbuck[dl][r] = (ushortT)(recs[q] >> DSH);
                }
            }
        }

        int nov = *ovfcnt;
        nov = nov > OCAP ? OCAP : nov;
        for (int i = tid; i < nov; i += 256) {
            unsigned rec = ovf[i];
            int d = rec & 0xFFFF;
            if ((d >> DSH) == b) {
                int r = atomicAdd(&lcnt[d & 255], 1);
                if (r < CAP) lbuck[d & 255][r] = (ushortT)(rec >> 16);
            }
        }
        __syncthreads();

        const int nbase = b << DSH;
        {
            int n = nbase + tid;
            if (n < NN) cnt[n] = lcnt[tid];
        }
        unsigned* ed = (unsigned*)(esorted + (size_t)nbase * CAP);
        const unsigned* ls = (const unsigned*)(&lbuck[0][0]);
        for (int i = tid; i < 256 * (CAP / 2); i += 256) {
            if (nbase + (i >> 5) < NN) ed[i] = ls[i];
        }
        return;
    }

    // ---- LDS-free GEMM1: 64x256 block, 2x2 waves, wave tile 32x128 ----
    const int w    = tid >> 6;
    const int lane = tid & 63;
    const int m16  = lane & 15;
    const int quad = lane >> 4;
    const int wr   = w >> 1;
    const int wc   = w & 1;
    const int gb   = blockIdx.x - BUCKB;
    const int rowbase = gb * 64 + wr * 32;
    const int colbase = wc * 128;

    const long r0 = min(rowbase + m16,      NN - 1);
    const long r1 = min(rowbase + 16 + m16, NN - 1);
    const float* a0p = x + r0 * 256 + quad * 8;
    const float* a1p = x + r1 * 256 + quad * 8;
    const ushortT* bp0 = W1T + (size_t)(colbase + m16) * 256 + quad * 8;

    floatx4 acc[2][8];
    #pragma unroll
    for (int i = 0; i < 2; ++i)
        #pragma unroll
        for (int j = 0; j < 8; ++j) acc[i][j] = (floatx4){0.f, 0.f, 0.f, 0.f};

    #pragma unroll
    for (int it = 0; it < 8; ++it) {
        const int k0 = it * 32;
        float4 fa00 = *(const float4*)(a0p + k0);
        float4 fa01 = *(const float4*)(a0p + k0 + 4);
        float4 fa10 = *(const float4*)(a1p + k0);
        float4 fa11 = *(const float4*)(a1p + k0 + 4);
        uint4 fb[8];
        #pragma unroll
        for (int j = 0; j < 8; ++j)
            fb[j] = *(const uint4*)(bp0 + (size_t)j * 16 * 256 + k0);

        ushortT a16[16];
        a16[0]=f2b(fa00.x); a16[1]=f2b(fa00.y); a16[2]=f2b(fa00.z); a16[3]=f2b(fa00.w);
        a16[4]=f2b(fa01.x); a16[5]=f2b(fa01.y); a16[6]=f2b(fa01.z); a16[7]=f2b(fa01.w);
        a16[8]=f2b(fa10.x); a16[9]=f2b(fa10.y); a16[10]=f2b(fa10.z); a16[11]=f2b(fa10.w);
        a16[12]=f2b(fa11.x); a16[13]=f2b(fa11.y); a16[14]=f2b(fa11.z); a16[15]=f2b(fa11.w);
        short8 af0 = *(short8*)(a16);
        short8 af1 = *(short8*)(a16 + 8);

        #pragma unroll
        for (int j = 0; j < 8; ++j) {
            short8 bf = *(short8*)(&fb[j]);
            acc[0][j] = __builtin_amdgcn_mfma_f32_16x16x32_bf16(af0, bf, acc[0][j], 0, 0, 0);
            acc[1][j] = __builtin_amdgcn_mfma_f32_16x16x32_bf16(af1, bf, acc[1][j], 0, 0, 0);
        }
    }

    float attSv[8], attDv[8];
    #pragma unroll
    for (int j = 0; j < 8; ++j) {
        attSv[j] = attS[colbase + j * 16 + m16];
        attDv[j] = attD[colbase + j * 16 + m16];
    }

    #pragma unroll
    for (int i = 0; i < 2; ++i) {
        #pragma unroll
        for (int r = 0; r < 4; ++r) {
            int row = rowbase + i * 16 + quad * 4 + r;
            bool ok = row < NN;
            if (ok) {
                #pragma unroll
                for (int j = 0; j < 8; ++j)
                    h1b[(size_t)row * 256 + colbase + j * 16 + m16] = f2b(acc[i][j][r]);
            }
            float d0 = 0.f, d1 = 0.f, e0 = 0.f, e1 = 0.f;
            #pragma unroll
            for (int jj = 0; jj < 4; ++jj) {
                d0 += acc[i][jj][r]     * attSv[jj];
                e0 += acc[i][jj][r]     * attDv[jj];
                d1 += acc[i][jj + 4][r] * attSv[jj + 4];
                e1 += acc[i][jj + 4][r] * attDv[jj + 4];
            }
            #pragma unroll
            for (int off = 1; off < 16; off <<= 1) {
                d0 += __shfl_xor(d0, off); e0 += __shfl_xor(e0, off);
                d1 += __shfl_xor(d1, off); e1 += __shfl_xor(e1, off);
            }
            if (ok && m16 == 0) {
                int hb = row * 4 + wc * 2;
                asrc[hb] = d0; asrc[hb + 1] = d1;
                adst[hb] = e0; adst[hb + 1] = e1;
            }
        }
    }
}

// ---------------------------------------------------------------------------
// agg1 (round-8 gather structure, fabric-floored) + FUSED layer-2 GEMM
// epilogue (round-10): after normalize+bias+elu the wave holds node n's full
// 256-col layer-2 input row in registers (lane = 4 cols). 64-step loop:
// broadcast lane q's 4 floats (readlane via unrolled uniform shfl), each
// lane j accumulates t2b[n][j] from packed W2P (512B contiguous per step,
// 32KB L1-resident). Kills the gemm2 dispatch, the a2b buffer, and 51MB of
// round-trip traffic. attS2/attD2 dots via one 6-shfl reduce.
// ---------------------------------------------------------------------------
__global__ __launch_bounds__(256) void agg1_k(const ushortT* __restrict__ esorted,
                                              const int* __restrict__ cnt,
                                              const ushortT* __restrict__ h1b,
                                              const float* __restrict__ asrc,
                                              const float* __restrict__ adst,
                                              const float* __restrict__ b1,
                                              const ushortT* __restrict__ W2P,
                                              const float* __restrict__ attS2,
                                              const float* __restrict__ attD2,
                                              ushortT* __restrict__ t2b,
                                              float* __restrict__ asrc2,
                                              float* __restrict__ adst2)
{
    __shared__ float pbuf[4][64][4];
    __shared__ int   sbuf[4][64];
    int w = threadIdx.x >> 6;
    int lane = threadIdx.x & 63;
    int n = blockIdx.x * 4 + w;
    if (n >= NN) return;
    int start = n * CAP;
    int deg = min(max(cnt[n], 0), CAP);
    float4 adv = *(const float4*)(adst + (size_t)n * 4);
    float4 asf = *(const float4*)(asrc + (size_t)n * 4);
    int h = lane >> 4;
    int c4 = lane * 4;

    // self-loop term
    float4 pself;
    pself.x = __expf(lrelu(asf.x + adv.x));
    pself.y = __expf(lrelu(asf.y + adv.y));
    pself.z = __expf(lrelu(asf.z + adv.z));
    pself.w = __expf(lrelu(asf.w + adv.w));
    float psh = (h < 2) ? (h == 0 ? pself.x : pself.y) : (h == 2 ? pself.z : pself.w);

    ushort4 hsv = *(const ushort4*)(h1b + (size_t)n * 256 + c4);
    float4 ac0 = make_float4(b2f(hsv.x) * psh, b2f(hsv.y) * psh, b2f(hsv.z) * psh, b2f(hsv.w) * psh);
    float4 ac1 = make_float4(0.f,0.f,0.f,0.f);
    float4 ac2 = make_float4(0.f,0.f,0.f,0.f);
    float4 ac3 = make_float4(0.f,0.f,0.f,0.f);
    float4 ssv = make_float4(0.f, 0.f, 0.f, 0.f);

    if (lane < deg) {
        int s = esorted[start + lane];
        float4 a = *(const float4*)(asrc + (size_t)s * 4);
        float4 pv;
        pv.x = __expf(lrelu(a.x + adv.x));
        pv.y = __expf(lrelu(a.y + adv.y));
        pv.z = __expf(lrelu(a.z + adv.z));
        pv.w = __expf(lrelu(a.w + adv.w));
        ssv = pv;
        *(float4*)(&pbuf[w][lane][0]) = pv;
        sbuf[w][lane] = s;
    } else {
        *(float4*)(&pbuf[w][lane][0]) = make_float4(0.f, 0.f, 0.f, 0.f);
        sbuf[w][lane] = 0;
    }
    __builtin_amdgcn_wave_barrier();   // intra-wave LDS write->read ordering

    int nb = (deg + 7) >> 3;           // 0..8
    ushort4 bufA[8], bufB[8];

#define LOADR(BUF, J0) { _Pragma("unroll") for (int q = 0; q < 8; ++q) { \
        int sq = sbuf[w][(J0) + q]; \
        BUF[q] = *(const ushort4*)(h1b + (size_t)sq * 256 + c4); } }
#define CONSR(BUF, J0) { _Pragma("unroll") for (int q = 0; q < 8; ++q) { \
        float p = pbuf[w][(J0) + q][h]; \
        float4* ac = (q & 3) == 0 ? &ac0 : (q & 3) == 1 ? &ac1 : (q & 3) == 2 ? &ac2 : &ac3; \
        ac->x += b2f(BUF[q].x) * p; ac->y += b2f(BUF[q].y) * p; \
        ac->z += b2f(BUF[q].z) * p; ac->w += b2f(BUF[q].w) * p; } }

    if (nb > 0) {
        LOADR(bufA, 0)
        #pragma unroll
        for (int b = 0; b < 8; ++b) {
            const int j0 = b << 3;
            if (b & 1) {
                if (b + 1 < nb) LOADR(bufA, j0 + 8)   // wave-uniform (nb per-node)
                CONSR(bufB, j0)
            } else {
                if (b + 1 < nb) LOADR(bufB, j0 + 8)
                CONSR(bufA, j0)
            }
            if (b + 1 >= nb) break;
        }
    }
#undef LOADR
#undef CONSR

    #pragma unroll
    for (int off = 1; off < 64; off <<= 1) {
        ssv.x += __shfl_xor(ssv.x, off); ssv.y += __shfl_xor(ssv.y, off);
        ssv.z += __shfl_xor(ssv.z, off); ssv.w += __shfl_xor(ssv.w, off);
    }
    float ssh = (h < 2) ? (h == 0 ? ssv.x : ssv.y) : (h == 2 ? ssv.z : ssv.w);
    float rdh = 1.f / (ssh + psh);

    float4 bv = *(const float4*)(b1 + c4);
    float f0 = eluf((ac0.x + ac1.x + ac2.x + ac3.x) * rdh + bv.x);
    float f1 = eluf((ac0.y + ac1.y + ac2.y + ac3.y) * rdh + bv.y);
    float f2 = eluf((ac0.z + ac1.z + ac2.z + ac3.z) * rdh + bv.z);
    float f3 = eluf((ac0.w + ac1.w + ac2.w + ac3.w) * rdh + bv.w);

    // ---- fused layer-2: t2b[n][lane] = sum_k rowf[k] * W2[k][lane] ----
    float acc2 = 0.f;
    const ushortT* wp = W2P + (size_t)lane * 4;
    #pragma unroll 8
    for (int q = 0; q < 64; ++q) {
        float b0 = __shfl(f0, q);
        float bb1 = __shfl(f1, q);
        float bb2 = __shfl(f2, q);
        float bb3 = __shfl(f3, q);
        ushort4 wv = *(const ushort4*)(wp + (size_t)q * 256);
        acc2 += b2f(wv.x) * b0 + b2f(wv.y) * bb1 + b2f(wv.z) * bb2 + b2f(wv.w) * bb3;
    }
    t2b[(size_t)n * 64 + lane] = f2b(acc2);
    float ds = acc2 * attS2[lane];
    float dd = acc2 * attD2[lane];
    #pragma unroll
    for (int off = 1; off < 64; off <<= 1) {
        ds += __shfl_xor(ds, off);
        dd += __shfl_xor(dd, off);
    }
    if (lane == 0) {
        asrc2[n] = ds;
        adst2[n] = dd;
    }
}

// ---------------------------------------------------------------------------
// agg2 (passing version, unchanged).
// ---------------------------------------------------------------------------
__global__ __launch_bounds__(256) void agg2_k(const ushortT* __restrict__ esorted,
                                              const int* __restrict__ cnt,
                                              const ushortT* __restrict__ t2b,
                                              const float* __restrict__ asrc,
                                              const float* __restrict__ adst,
                                              const float* __restrict__ b2,
                                              float* __restrict__ out)
{
    __shared__ float pbuf[4][64];
    __shared__ int   sbuf[4][64];
    int w = threadIdx.x >> 6;
    int lane = threadIdx.x & 63;
    int n = blockIdx.x * 4 + w;
    if (n >= NN) return;
    int start = n * CAP;
    int deg = min(max(cnt[n], 0), CAP);
    float adv = adst[n];

    float pself = __expf(lrelu(asrc[n] + adv));
    float a0 = b2f(t2b[(size_t)n * 64 + lane]) * pself;
    float a1 = 0.f, a2 = 0.f, a3 = 0.f;
    float ss = 0.f;

    if (lane < deg) {
        int s = esorted[start + lane];
        float p = __expf(lrelu(asrc[s] + adv));
        ss = p;
        pbuf[w][lane] = p;
        sbuf[w][lane] = s;
    } else {
        pbuf[w][lane] = 0.f;
        sbuf[w][lane] = 0;
    }
    __builtin_amdgcn_wave_barrier();

    int nb = (deg + 7) >> 3;           // 0..8
    ushortT bufA[8], bufB[8];

#define LOADR2(BUF, J0) { _Pragma("unroll") for (int q = 0; q < 8; ++q) { \
        int sq = sbuf[w][(J0) + q]; \
        BUF[q] = t2b[(size_t)sq * 64 + lane]; } }
#define CONSR2(BUF, J0) { _Pragma("unroll") for (int q = 0; q < 8; ++q) { \
        float p = pbuf[w][(J0) + q]; \
        float* ac = (q & 3) == 0 ? &a0 : (q & 3) == 1 ? &a1 : (q & 3) == 2 ? &a2 : &a3; \
        *ac += b2f(BUF[q]) * p; } }

    if (nb > 0) {
        LOADR2(bufA, 0)
        #pragma unroll
        for (int b = 0; b < 8; ++b) {
            const int j0 = b << 3;
            if (b & 1) {
                if (b + 1 < nb) LOADR2(bufA, j0 + 8)
                CONSR2(bufB, j0)
            } else {
                if (b + 1 < nb) LOADR2(bufB, j0 + 8)
                CONSR2(bufA, j0)
            }
            if (b + 1 >= nb) break;
        }
    }
#undef LOADR2
#undef CONSR2

    #pragma unroll
    for (int off = 1; off < 64; off <<= 1) ss += __shfl_xor(ss, off);
    float v = (a0 + a1 + a2 + a3) / (ss + pself) + b2[lane];

    float m2 = v;
    #pragma unroll
    for (int off = 32; off; off >>= 1) m2 = fmaxf(m2, __shfl_xor(m2, off));
    float ex = __expf(v - m2);
    float sm = ex;
    #pragma unroll
    for (int off = 32; off; off >>= 1) sm += __shfl_xor(sm, off);
    out[(size_t)n * 64 + lane] = v - m2 - __logf(sm);
}

// ---------------------------------------------------------------------------
extern "C" void kernel_launch(void* const* d_in, const int* in_sizes, int n_in,
                              void* d_out, int out_size, void* d_ws, size_t ws_size,
                              hipStream_t stream)
{
    const float* x   = (const float*)d_in[0];
    const int*   adj = (const int*)  d_in[1];
    const float* W1  = (const float*)d_in[2];
    const float* as1 = (const float*)d_in[3];
    const float* ad1 = (const float*)d_in[4];
    const float* b1  = (const float*)d_in[5];
    const float* W2  = (const float*)d_in[6];
    const float* as2 = (const float*)d_in[7];
    const float* ad2 = (const float*)d_in[8];
    const float* b2  = (const float*)d_in[9];
    float* out = (float*)d_out;

    const size_t szH1b = (size_t)NN * 256 * 2;           // 25.6 MB
    const size_t szT2b = (size_t)NN * 64 * 2;            // 6.4 MB
    const size_t szA4  = (size_t)NN * 4 * 4;             // 0.8 MB
    const size_t szA1  = (size_t)NN * 4;                 // 0.2 MB
    const size_t szE   = (size_t)NN * CAP * 2;           // 6.4 MB (ushort buckets)
    const size_t szBin = (size_t)NBIN * PBLK * BCAP * 4; // 11.2 MB (phase-1 records)
    const size_t szC2  = (size_t)PBLK * NBIN * 2;        // 0.4 MB (per-(block,bin) counts)

    char* p = (char*)d_ws;
    ushortT* h1b  = (ushortT*)p; p += szH1b;
    ushortT* t2b  = (ushortT*)p; p += szT2b;
    ushortT* W1T  = (ushortT*)p; p += 256 * 256 * 2;
    ushortT* W2P  = (ushortT*)p; p += 64 * 256 * 2;      // packed [q][j][r]
    float* asrc1  = (float*)p; p += szA4;
    float* adst1  = (float*)p; p += szA4;
    float* asrc2  = (float*)p; p += szA1;
    float* adst2  = (float*)p; p += szA1;
    ushortT* esorted = (ushortT*)p; p += szE;
    int* cnt      = (int*)p; p += szA1;
    unsigned* binned = (unsigned*)p; p += szBin;
    ushortT* cnt2 = (ushortT*)p; p += szC2;
    unsigned* ovf = (unsigned*)p; p += (size_t)OCAP * 4;
    int* ovfcnt   = (int*)p; p += 64;

    const int nwb = (NN + 3) / 4;       // 12500

    // overflow-counter zero (graph-capture-legal async memset)
    hipMemsetAsync(ovfcnt, 0, sizeof(int), stream);

    // d1: weight prep (blocks 0..19, hides under bin) + phase-1 binning
    binCast_k<<<CASTB + PBLK, 256, 0, stream>>>(adj, adj + EE, binned, cnt2, ovf, ovfcnt,
                                                W1, W2, W1T, W2P);

    // d2: bucket assembly (blocks 0..195, hides under gemm) + layer-1 GEMM
    gembucket_k<<<BUCKB + MT64, 256, 0, stream>>>(x, W1T, as1, ad1, h1b, asrc1, adst1,
                                                  binned, cnt2, ovf, ovfcnt, esorted, cnt);

    // agg1 + fused layer-2 GEMM epilogue (gemm2 dispatch + a2b buffer gone)
    agg1_k<<<nwb, 256, 0, stream>>>(esorted, cnt, h1b, asrc1, adst1, b1,
                                    W2P, as2, ad2, t2b, asrc2, adst2);

    agg2_k<<<nwb, 256, 0, stream>>>(esorted, cnt, t2b, asrc2, adst2, b2, out);
}

// Round 11
// 266.140 us; speedup vs baseline: 1.3565x; 1.2957x over previous
//
#include <hip/hip_runtime.h>
#include <cstdint>
#include <cstddef>

// Problem constants
#define NN    50000
#define EE    800000   /* graph edges; self-loops handled analytically in agg */
#define SLOPE 0.2f
#define MT64  782      /* (NN+63)/64 row-blocks */
#define CAP   64       /* per-node bucket capacity (in-deg Poisson(16), P(>=64)~1e-20) */

// Two-level binning scatter. Round-7: oversubscribed fused grids run blocks
// in ID order -> small phase FIRST hides under the bulk.
// Round-9: XCD-slicing agg1 halved FETCH but 2.5x'd time (instruction-bound).
// Round-10: fusing gemm2 into agg1 via shfl-broadcast = 256 bpermute/node ->
// agg1 66->183us. BOTH REVERTED: aggregation waves have no instruction
// headroom; only scheduling/traffic changes pay, never per-wave recompute.
// This round: round-8 structure + launch_bounds 3->4 on the fused kernels
// (LDS 28.4/35KB x4 <= 160KB, VGPR 68 <= 128) for +33% occupancy on the
// latency-bound gemm/bin phases.
#define NBIN  196
#define DSH   8        /* dst>>DSH = bin; 256 nodes per bin */
#define PBLK  1024     /* phase-1 scatter blocks */
#define EPB   782      /* ceil(EE/PBLK) */
#define BCAP  14       /* per-(block,bin) cap; lambda~4.0, P(Pois(4)>14)~2e-5 */
#define OCAP  8192     /* global overflow list capacity */
#define CASTB 20       /* 16 W1 64x64 tiles + 4 W2 tiles */
#define BUCKB NBIN     /* bucket blocks, first in d2 */

typedef unsigned short ushortT;
typedef __attribute__((ext_vector_type(8))) short short8;
typedef __attribute__((ext_vector_type(4))) float floatx4;

__device__ __forceinline__ float lrelu(float x){ return x > 0.f ? x : SLOPE * x; }
__device__ __forceinline__ float eluf(float x){ return x > 0.f ? x : __expf(x) - 1.f; }
__device__ __forceinline__ ushortT f2b(float f){ unsigned u = __float_as_uint(f); u += 0x7fff + ((u >> 16) & 1); return (ushortT)(u >> 16); }
__device__ __forceinline__ float   b2f(ushortT b){ return __uint_as_float(((unsigned)b) << 16); }

// ---------------------------------------------------------------------------
// d1: blocks [0,CASTB) = LDS-tiled weight transpose-cast (coalesced writes);
// blocks [CASTB,..) = phase-1 edge binning. castW first, hides under binning.
// ---------------------------------------------------------------------------
__global__ __launch_bounds__(256, 4) void binCast_k(const int* __restrict__ srcA,
                                                    const int* __restrict__ dstA,
                                                    unsigned* __restrict__ binned,
                                                    ushortT* __restrict__ cnt2,
                                                    unsigned* __restrict__ ovf,
                                                    int* __restrict__ ovfcnt,
                                                    const float* __restrict__ W1,
                                                    const float* __restrict__ W2,
                                                    ushortT* __restrict__ W1T,
                                                    ushortT* __restrict__ W2T)
{
    __shared__ float    tile[64][65];        // 16.6 KB (transpose staging)
    __shared__ int      hist[NBIN];          // 784 B
    __shared__ unsigned lrec[NBIN][BCAP];    // 11 KB

    const int tid = threadIdx.x;
    if (blockIdx.x < CASTB) {
        const int lr = tid >> 6;       // 0..3
        const int lc = tid & 63;       // 0..63
        if (blockIdx.x < 16) {
            const int tr = blockIdx.x >> 2, tc = blockIdx.x & 3;
            #pragma unroll
            for (int i = 0; i < 16; ++i) {
                int r = lr + i * 4;
                tile[r][lc] = W1[(size_t)(tr * 64 + r) * 256 + tc * 64 + lc];
            }
            __syncthreads();
            #pragma unroll
            for (int i = 0; i < 16; ++i) {
                int r = lr + i * 4;
                W1T[(size_t)(tc * 64 + r) * 256 + tr * 64 + lc] = f2b(tile[lc][r]);
            }
        } else {
            const int tk = blockIdx.x - 16;   // 0..3 over k
            #pragma unroll
            for (int i = 0; i < 16; ++i) {
                int r = lr + i * 4;
                tile[r][lc] = W2[(size_t)(tk * 64 + r) * 64 + lc];
            }
            __syncthreads();
            #pragma unroll
            for (int i = 0; i < 16; ++i) {
                int r = lr + i * 4;
                W2T[(size_t)r * 256 + tk * 64 + lc] = f2b(tile[lc][r]);
            }
        }
        return;
    }

    // ---- phase-1 binning ----
    const int blk = blockIdx.x - CASTB;
    for (int i = tid; i < NBIN; i += 256) hist[i] = 0;
    __syncthreads();

    const int e0 = blk * EPB;
    const int e1 = min(e0 + EPB, EE);
    for (int e = e0 + tid; e < e1; e += 256) {
        int s = srcA[e], d = dstA[e];
        int bin = d >> DSH;
        unsigned rec = ((unsigned)s << DSH) | (unsigned)(d & 255);
        int r = atomicAdd(&hist[bin], 1);
        if (r < BCAP) lrec[bin][r] = rec;
        else {
            int o = atomicAdd(ovfcnt, 1);
            if (o < OCAP) ovf[o] = ((unsigned)s << 16) | (unsigned)d;
        }
    }
    __syncthreads();

    for (int b = tid; b < NBIN; b += 256)
        cnt2[(size_t)blk * NBIN + b] = (ushortT)min(hist[b], BCAP);
    // transposed coalesced writeback (consecutive sIdx -> consecutive addr)
    for (int sIdx = tid; sIdx < NBIN * BCAP; sIdx += 256) {
        int b = sIdx / BCAP;
        int i = sIdx - b * BCAP;
        if (i < min(hist[b], BCAP))
            binned[((size_t)blk * NBIN + b) * BCAP + i] = lrec[b][i];
    }
}

// ---------------------------------------------------------------------------
// d2: blocks [0,BUCKB) = phase-2 bucket assembly (first, hides under GEMM;
// x8-batched strided gather); blocks [BUCKB,..) = layer-1 GEMM (LDS-free).
// ---------------------------------------------------------------------------
__global__ __launch_bounds__(256, 4) void gembucket_k(const float* __restrict__ x,
                                                      const ushortT* __restrict__ W1T,
                                                      const float* __restrict__ attS,
                                                      const float* __restrict__ attD,
                                                      ushortT* __restrict__ h1b,
                                                      float* __restrict__ asrc,
                                                      float* __restrict__ adst,
                                                      const unsigned* __restrict__ binned,
                                                      const ushortT* __restrict__ cnt2,
                                                      const unsigned* __restrict__ ovf,
                                                      const int* __restrict__ ovfcnt,
                                                      ushortT* __restrict__ esorted,
                                                      int* __restrict__ cnt)
{
    __shared__ ushortT c2[PBLK];          // 2 KB
    __shared__ int     lcnt[256];         // 1 KB
    __shared__ ushortT lbuck[256][CAP];   // 32 KB (35 KB total; 4 blk/CU = 140 KB ok)

    const int tid = threadIdx.x;
    if (blockIdx.x < BUCKB) {
        const int b = blockIdx.x;
        lcnt[tid] = 0;
        for (int i = tid; i < PBLK; i += 256) c2[i] = cnt2[(size_t)i * NBIN + b];
        __syncthreads();

        for (int s0 = tid; s0 < PBLK * BCAP; s0 += 2048) {
            unsigned recs[8]; int ok[8];
            #pragma unroll
            for (int q = 0; q < 8; ++q) {
                int s = s0 + q * 256;
                int blk = s / BCAP;
                int i = s - blk * BCAP;
                ok[q] = (i < (int)c2[blk]);
                recs[q] = ok[q] ? binned[((size_t)blk * NBIN + b) * BCAP + i] : 0u;
            }
            #pragma unroll
            for (int q = 0; q < 8; ++q) {
                if (ok[q]) {
                    int dl = recs[q] & 255;
                    int r = atomicAdd(&lcnt[dl], 1);
                    if (r < CAP) lbuck[dl][r] = (ushortT)(recs[q] >> DSH);
                }
            }
        }

        int nov = *ovfcnt;
        nov = nov > OCAP ? OCAP : nov;
        for (int i = tid; i < nov; i += 256) {
            unsigned rec = ovf[i];
            int d = rec & 0xFFFF;
            if ((d >> DSH) == b) {
                int r = atomicAdd(&lcnt[d & 255], 1);
                if (r < CAP) lbuck[d & 255][r] = (ushortT)(rec >> 16);
            }
        }
        __syncthreads();

        const int nbase = b << DSH;
        {
            int n = nbase + tid;
            if (n < NN) cnt[n] = lcnt[tid];
        }
        unsigned* ed = (unsigned*)(esorted + (size_t)nbase * CAP);
        const unsigned* ls = (const unsigned*)(&lbuck[0][0]);
        for (int i = tid; i < 256 * (CAP / 2); i += 256) {
            if (nbase + (i >> 5) < NN) ed[i] = ls[i];
        }
        return;
    }

    // ---- LDS-free GEMM1: 64x256 block, 2x2 waves, wave tile 32x128 ----
    const int w    = tid >> 6;
    const int lane = tid & 63;
    const int m16  = lane & 15;
    const int quad = lane >> 4;
    const int wr   = w >> 1;
    const int wc   = w & 1;
    const int gb   = blockIdx.x - BUCKB;
    const int rowbase = gb * 64 + wr * 32;
    const int colbase = wc * 128;

    const long r0 = min(rowbase + m16,      NN - 1);
    const long r1 = min(rowbase + 16 + m16, NN - 1);
    const float* a0p = x + r0 * 256 + quad * 8;
    const float* a1p = x + r1 * 256 + quad * 8;
    const ushortT* bp0 = W1T + (size_t)(colbase + m16) * 256 + quad * 8;

    floatx4 acc[2][8];
    #pragma unroll
    for (int i = 0; i < 2; ++i)
        #pragma unroll
        for (int j = 0; j < 8; ++j) acc[i][j] = (floatx4){0.f, 0.f, 0.f, 0.f};

    #pragma unroll
    for (int it = 0; it < 8; ++it) {
        const int k0 = it * 32;
        float4 fa00 = *(const float4*)(a0p + k0);
        float4 fa01 = *(const float4*)(a0p + k0 + 4);
        float4 fa10 = *(const float4*)(a1p + k0);
        float4 fa11 = *(const float4*)(a1p + k0 + 4);
        uint4 fb[8];
        #pragma unroll
        for (int j = 0; j < 8; ++j)
            fb[j] = *(const uint4*)(bp0 + (size_t)j * 16 * 256 + k0);

        ushortT a16[16];
        a16[0]=f2b(fa00.x); a16[1]=f2b(fa00.y); a16[2]=f2b(fa00.z); a16[3]=f2b(fa00.w);
        a16[4]=f2b(fa01.x); a16[5]=f2b(fa01.y); a16[6]=f2b(fa01.z); a16[7]=f2b(fa01.w);
        a16[8]=f2b(fa10.x); a16[9]=f2b(fa10.y); a16[10]=f2b(fa10.z); a16[11]=f2b(fa10.w);
        a16[12]=f2b(fa11.x); a16[13]=f2b(fa11.y); a16[14]=f2b(fa11.z); a16[15]=f2b(fa11.w);
        short8 af0 = *(short8*)(a16);
        short8 af1 = *(short8*)(a16 + 8);

        #pragma unroll
        for (int j = 0; j < 8; ++j) {
            short8 bf = *(short8*)(&fb[j]);
            acc[0][j] = __builtin_amdgcn_mfma_f32_16x16x32_bf16(af0, bf, acc[0][j], 0, 0, 0);
            acc[1][j] = __builtin_amdgcn_mfma_f32_16x16x32_bf16(af1, bf, acc[1][j], 0, 0, 0);
        }
    }

    float attSv[8], attDv[8];
    #pragma unroll
    for (int j = 0; j < 8; ++j) {
        attSv[j] = attS[colbase + j * 16 + m16];
        attDv[j] = attD[colbase + j * 16 + m16];
    }

    #pragma unroll
    for (int i = 0; i < 2; ++i) {
        #pragma unroll
        for (int r = 0; r < 4; ++r) {
            int row = rowbase + i * 16 + quad * 4 + r;
            bool ok = row < NN;
            if (ok) {
                #pragma unroll
                for (int j = 0; j < 8; ++j)
                    h1b[(size_t)row * 256 + colbase + j * 16 + m16] = f2b(acc[i][j][r]);
            }
            float d0 = 0.f, d1 = 0.f, e0 = 0.f, e1 = 0.f;
            #pragma unroll
            for (int jj = 0; jj < 4; ++jj) {
                d0 += acc[i][jj][r]     * attSv[jj];
                e0 += acc[i][jj][r]     * attDv[jj];
                d1 += acc[i][jj + 4][r] * attSv[jj + 4];
                e1 += acc[i][jj + 4][r] * attDv[jj + 4];
            }
            #pragma unroll
            for (int off = 1; off < 16; off <<= 1) {
                d0 += __shfl_xor(d0, off); e0 += __shfl_xor(e0, off);
                d1 += __shfl_xor(d1, off); e1 += __shfl_xor(e1, off);
            }
            if (ok && m16 == 0) {
                int hb = row * 4 + wc * 2;
                asrc[hb] = d0; asrc[hb + 1] = d1;
                adst[hb] = e0; adst[hb + 1] = e1;
            }
        }
    }
}

// ---------------------------------------------------------------------------
// Layer-2 GEMM, LDS-free. Wave tile 16x64; 4 waves stacked = 64 rows.
// ---------------------------------------------------------------------------
__global__ __launch_bounds__(256) void gemm2_k(const ushortT* __restrict__ a2b,
                                               const ushortT* __restrict__ W2T,
                                               const float* __restrict__ attS,
                                               const float* __restrict__ attD,
                                               ushortT* __restrict__ t2b,
                                               float* __restrict__ asrc,
                                               float* __restrict__ adst)
{
    const int tid  = threadIdx.x;
    const int w    = tid >> 6;
    const int lane = tid & 63;
    const int m16  = lane & 15;
    const int quad = lane >> 4;
    const int rowbase = blockIdx.x * 64 + w * 16;

    const long r0 = min(rowbase + m16, NN - 1);
    const ushortT* ap  = a2b + r0 * 256 + quad * 8;
    const ushortT* bp0 = W2T + (size_t)m16 * 256 + quad * 8;

    floatx4 acc[4];
    #pragma unroll
    for (int j = 0; j < 4; ++j) acc[j] = (floatx4){0.f, 0.f, 0.f, 0.f};

    #pragma unroll
    for (int it = 0; it < 8; ++it) {
        const int k0 = it * 32;
        uint4 fa = *(const uint4*)(ap + k0);
        uint4 fb[4];
        #pragma unroll
        for (int j = 0; j < 4; ++j)
            fb[j] = *(const uint4*)(bp0 + (size_t)j * 16 * 256 + k0);
        short8 af = *(short8*)(&fa);
        #pragma unroll
        for (int j = 0; j < 4; ++j) {
            short8 bf = *(short8*)(&fb[j]);
            acc[j] = __builtin_amdgcn_mfma_f32_16x16x32_bf16(af, bf, acc[j], 0, 0, 0);
        }
    }

    float attSv[4], attDv[4];
    #pragma unroll
    for (int j = 0; j < 4; ++j) {
        attSv[j] = attS[j * 16 + m16];
        attDv[j] = attD[j * 16 + m16];
    }

    #pragma unroll
    for (int r = 0; r < 4; ++r) {
        int row = rowbase + quad * 4 + r;
        bool ok = row < NN;
        if (ok) {
            #pragma unroll
            for (int j = 0; j < 4; ++j)
                t2b[(size_t)row * 64 + j * 16 + m16] = f2b(acc[j][r]);
        }
        float ds = 0.f, dd = 0.f;
        #pragma unroll
        for (int j = 0; j < 4; ++j) {
            ds += acc[j][r] * attSv[j];
            dd += acc[j][r] * attDv[j];
        }
        #pragma unroll
        for (int off = 1; off < 16; off <<= 1) {
            ds += __shfl_xor(ds, off);
            dd += __shfl_xor(dd, off);
        }
        if (ok && m16 == 0) {
            asrc[row] = ds;
            adst[row] = dd;
        }
    }
}

// ---------------------------------------------------------------------------
// agg1 (round-8 passing version): fabric-floored (~3.7TB/s, 8 XCDs x h1b).
// ---------------------------------------------------------------------------
__global__ __launch_bounds__(256) void agg1_k(const ushortT* __restrict__ esorted,
                                              const int* __restrict__ cnt,
                                              const ushortT* __restrict__ h1b,
                                              const float* __restrict__ asrc,
                                              const float* __restrict__ adst,
                                              const float* __restrict__ b1,
                                              ushortT* __restrict__ a2b)
{
    __shared__ float pbuf[4][64][4];
    __shared__ int   sbuf[4][64];
    int w = threadIdx.x >> 6;
    int lane = threadIdx.x & 63;
    int n = blockIdx.x * 4 + w;
    if (n >= NN) return;
    int start = n * CAP;
    int deg = min(max(cnt[n], 0), CAP);
    float4 adv = *(const float4*)(adst + (size_t)n * 4);
    float4 asf = *(const float4*)(asrc + (size_t)n * 4);
    int h = lane >> 4;
    int c4 = lane * 4;

    // self-loop term
    float4 pself;
    pself.x = __expf(lrelu(asf.x + adv.x));
    pself.y = __expf(lrelu(asf.y + adv.y));
    pself.z = __expf(lrelu(asf.z + adv.z));
    pself.w = __expf(lrelu(asf.w + adv.w));
    float psh = (h < 2) ? (h == 0 ? pself.x : pself.y) : (h == 2 ? pself.z : pself.w);

    ushort4 hsv = *(const ushort4*)(h1b + (size_t)n * 256 + c4);
    float4 ac0 = make_float4(b2f(hsv.x) * psh, b2f(hsv.y) * psh, b2f(hsv.z) * psh, b2f(hsv.w) * psh);
    float4 ac1 = make_float4(0.f,0.f,0.f,0.f);
    float4 ac2 = make_float4(0.f,0.f,0.f,0.f);
    float4 ac3 = make_float4(0.f,0.f,0.f,0.f);
    float4 ssv = make_float4(0.f, 0.f, 0.f, 0.f);

    if (lane < deg) {
        int s = esorted[start + lane];
        float4 a = *(const float4*)(asrc + (size_t)s * 4);
        float4 pv;
        pv.x = __expf(lrelu(a.x + adv.x));
        pv.y = __expf(lrelu(a.y + adv.y));
        pv.z = __expf(lrelu(a.z + adv.z));
        pv.w = __expf(lrelu(a.w + adv.w));
        ssv = pv;
        *(float4*)(&pbuf[w][lane][0]) = pv;
        sbuf[w][lane] = s;
    } else {
        *(float4*)(&pbuf[w][lane][0]) = make_float4(0.f, 0.f, 0.f, 0.f);
        sbuf[w][lane] = 0;
    }
    __builtin_amdgcn_wave_barrier();   // intra-wave LDS write->read ordering

    int nb = (deg + 7) >> 3;           // 0..8
    ushort4 bufA[8], bufB[8];

#define LOADR(BUF, J0) { _Pragma("unroll") for (int q = 0; q < 8; ++q) { \
        int sq = sbuf[w][(J0) + q]; \
        BUF[q] = *(const ushort4*)(h1b + (size_t)sq * 256 + c4); } }
#define CONSR(BUF, J0) { _Pragma("unroll") for (int q = 0; q < 8; ++q) { \
        float p = pbuf[w][(J0) + q][h]; \
        float4* ac = (q & 3) == 0 ? &ac0 : (q & 3) == 1 ? &ac1 : (q & 3) == 2 ? &ac2 : &ac3; \
        ac->x += b2f(BUF[q].x) * p; ac->y += b2f(BUF[q].y) * p; \
        ac->z += b2f(BUF[q].z) * p; ac->w += b2f(BUF[q].w) * p; } }

    if (nb > 0) {
        LOADR(bufA, 0)
        #pragma unroll
        for (int b = 0; b < 8; ++b) {
            const int j0 = b << 3;
            if (b & 1) {
                if (b + 1 < nb) LOADR(bufA, j0 + 8)   // wave-uniform (nb per-node)
                CONSR(bufB, j0)
            } else {
                if (b + 1 < nb) LOADR(bufB, j0 + 8)
                CONSR(bufA, j0)
            }
            if (b + 1 >= nb) break;
        }
    }
#undef LOADR
#undef CONSR

    #pragma unroll
    for (int off = 1; off < 64; off <<= 1) {
        ssv.x += __shfl_xor(ssv.x, off); ssv.y += __shfl_xor(ssv.y, off);
        ssv.z += __shfl_xor(ssv.z, off); ssv.w += __shfl_xor(ssv.w, off);
    }
    float ssh = (h < 2) ? (h == 0 ? ssv.x : ssv.y) : (h == 2 ? ssv.z : ssv.w);
    float rdh = 1.f / (ssh + psh);

    float4 bv = *(const float4*)(b1 + c4);
    ushort4 o;
    o.x = f2b(eluf((ac0.x + ac1.x + ac2.x + ac3.x) * rdh + bv.x));
    o.y = f2b(eluf((ac0.y + ac1.y + ac2.y + ac3.y) * rdh + bv.y));
    o.z = f2b(eluf((ac0.z + ac1.z + ac2.z + ac3.z) * rdh + bv.z));
    o.w = f2b(eluf((ac0.w + ac1.w + ac2.w + ac3.w) * rdh + bv.w));
    *(ushort4*)(a2b + (size_t)n * 256 + c4) = o;
}

// ---------------------------------------------------------------------------
// agg2 (round-8 passing version, unchanged).
// ---------------------------------------------------------------------------
__global__ __launch_bounds__(256) void agg2_k(const ushortT* __restrict__ esorted,
                                              const int* __restrict__ cnt,
                                              const ushortT* __restrict__ t2b,
                                              const float* __restrict__ asrc,
                                              const float* __restrict__ adst,
                                              const float* __restrict__ b2,
                                              float* __restrict__ out)
{
    __shared__ float pbuf[4][64];
    __shared__ int   sbuf[4][64];
    int w = threadIdx.x >> 6;
    int lane = threadIdx.x & 63;
    int n = blockIdx.x * 4 + w;
    if (n >= NN) return;
    int start = n * CAP;
    int deg = min(max(cnt[n], 0), CAP);
    float adv = adst[n];

    float pself = __expf(lrelu(asrc[n] + adv));
    float a0 = b2f(t2b[(size_t)n * 64 + lane]) * pself;
    float a1 = 0.f, a2 = 0.f, a3 = 0.f;
    float ss = 0.f;

    if (lane < deg) {
        int s = esorted[start + lane];
        float p = __expf(lrelu(asrc[s] + adv));
        ss = p;
        pbuf[w][lane] = p;
        sbuf[w][lane] = s;
    } else {
        pbuf[w][lane] = 0.f;
        sbuf[w][lane] = 0;
    }
    __builtin_amdgcn_wave_barrier();

    int nb = (deg + 7) >> 3;           // 0..8
    ushortT bufA[8], bufB[8];

#define LOADR2(BUF, J0) { _Pragma("unroll") for (int q = 0; q < 8; ++q) { \
        int sq = sbuf[w][(J0) + q]; \
        BUF[q] = t2b[(size_t)sq * 64 + lane]; } }
#define CONSR2(BUF, J0) { _Pragma("unroll") for (int q = 0; q < 8; ++q) { \
        float p = pbuf[w][(J0) + q]; \
        float* ac = (q & 3) == 0 ? &a0 : (q & 3) == 1 ? &a1 : (q & 3) == 2 ? &a2 : &a3; \
        *ac += b2f(BUF[q]) * p; } }

    if (nb > 0) {
        LOADR2(bufA, 0)
        #pragma unroll
        for (int b = 0; b < 8; ++b) {
            const int j0 = b << 3;
            if (b & 1) {
                if (b + 1 < nb) LOADR2(bufA, j0 + 8)
                CONSR2(bufB, j0)
            } else {
                if (b + 1 < nb) LOADR2(bufB, j0 + 8)
                CONSR2(bufA, j0)
            }
            if (b + 1 >= nb) break;
        }
    }
#undef LOADR2
#undef CONSR2

    #pragma unroll
    for (int off = 1; off < 64; off <<= 1) ss += __shfl_xor(ss, off);
    float v = (a0 + a1 + a2 + a3) / (ss + pself) + b2[lane];

    float m2 = v;
    #pragma unroll
    for (int off = 32; off; off >>= 1) m2 = fmaxf(m2, __shfl_xor(m2, off));
    float ex = __expf(v - m2);
    float sm = ex;
    #pragma unroll
    for (int off = 32; off; off >>= 1) sm += __shfl_xor(sm, off);
    out[(size_t)n * 64 + lane] = v - m2 - __logf(sm);
}

// ---------------------------------------------------------------------------
extern "C" void kernel_launch(void* const* d_in, const int* in_sizes, int n_in,
                              void* d_out, int out_size, void* d_ws, size_t ws_size,
                              hipStream_t stream)
{
    const float* x   = (const float*)d_in[0];
    const int*   adj = (const int*)  d_in[1];
    const float* W1  = (const float*)d_in[2];
    const float* as1 = (const float*)d_in[3];
    const float* ad1 = (const float*)d_in[4];
    const float* b1  = (const float*)d_in[5];
    const float* W2  = (const float*)d_in[6];
    const float* as2 = (const float*)d_in[7];
    const float* ad2 = (const float*)d_in[8];
    const float* b2  = (const float*)d_in[9];
    float* out = (float*)d_out;

    const size_t szH1b = (size_t)NN * 256 * 2;           // 25.6 MB
    const size_t szT2b = (size_t)NN * 64 * 2;            // 6.4 MB
    const size_t szA4  = (size_t)NN * 4 * 4;             // 0.8 MB
    const size_t szA1  = (size_t)NN * 4;                 // 0.2 MB
    const size_t szE   = (size_t)NN * CAP * 2;           // 6.4 MB (ushort buckets)
    const size_t szBin = (size_t)NBIN * PBLK * BCAP * 4; // 11.2 MB (phase-1 records)
    const size_t szC2  = (size_t)PBLK * NBIN * 2;        // 0.4 MB (per-(block,bin) counts)

    char* p = (char*)d_ws;
    ushortT* h1b  = (ushortT*)p; p += szH1b;
    ushortT* a2b  = (ushortT*)p; p += szH1b;
    ushortT* t2b  = (ushortT*)p; p += szT2b;
    ushortT* W1T  = (ushortT*)p; p += 256 * 256 * 2;
    ushortT* W2T  = (ushortT*)p; p += 64 * 256 * 2;
    float* asrc1  = (float*)p; p += szA4;
    float* adst1  = (float*)p; p += szA4;
    float* asrc2  = (float*)p; p += szA1;
    float* adst2  = (float*)p; p += szA1;
    ushortT* esorted = (ushortT*)p; p += szE;
    int* cnt      = (int*)p; p += szA1;
    unsigned* binned = (unsigned*)p; p += szBin;
    ushortT* cnt2 = (ushortT*)p; p += szC2;
    unsigned* ovf = (unsigned*)p; p += (size_t)OCAP * 4;
    int* ovfcnt   = (int*)p; p += 64;

    const int nwb = (NN + 3) / 4;       // 12500

    // overflow-counter zero (graph-capture-legal async memset)
    hipMemsetAsync(ovfcnt, 0, sizeof(int), stream);

    // d1: LDS-tiled castW (blocks 0..19, hides under bin) + phase-1 binning
    binCast_k<<<CASTB + PBLK, 256, 0, stream>>>(adj, adj + EE, binned, cnt2, ovf, ovfcnt,
                                                W1, W2, W1T, W2T);

    // d2: bucket assembly (blocks 0..195, hides under gemm) + layer-1 GEMM
    gembucket_k<<<BUCKB + MT64, 256, 0, stream>>>(x, W1T, as1, ad1, h1b, asrc1, adst1,
                                                  binned, cnt2, ovf, ovfcnt, esorted, cnt);

    agg1_k<<<nwb, 256, 0, stream>>>(esorted, cnt, h1b, asrc1, adst1, b1, a2b);
    gemm2_k<<<MT64, 256, 0, stream>>>(a2b, W2T, as2, ad2, t2b, asrc2, adst2);
    agg2_k<<<nwb, 256, 0, stream>>>(esorted, cnt, t2b, asrc2, adst2, b2, out);
}